// Round 1
// baseline (120.912 us; speedup 1.0000x reference)
//
#include <hip/hip_runtime.h>
#include <hip/hip_fp16.h>
#include <math.h>

#define DET 512
#define NA 180
#define NTILES 1024                   // 32 x 32 tiles of 16x16 pixels
#define TANG_FLOATS (NTILES * NA * 4) // 2.95 MB
#define CHUNK 20                      // angles per staged chunk (was 10)
#define WWIN 24
#define NCH 9                         // 9 chunks x 20 angles = 180 (full sweep, single writer)
#define NSLOT (CHUNK * WWIN * 2)      // 960 uint4 slots per chunk (30.7 KB x 2 buffers)
#define ZERO_IDX (NA * DET * 2)       // zero uint4 slot index in xsT2

typedef _Float16 half2_t __attribute__((ext_vector_type(2)));

// direct global->LDS DMA, 16 B per lane; lds dest = wave-uniform base + lane*16
__device__ __forceinline__ void async_copy16(void* lds, const void* g) {
    __builtin_amdgcn_global_load_lds(
        (const __attribute__((address_space(1))) unsigned*)g,
        (__attribute__((address_space(3))) unsigned*)(unsigned)(unsigned long long)lds,
        16, 0, 0);
}

// ws layout (floats):
//  [0, TANG_FLOATS)  : tang float4 per (tile,angle): {bias=255.5-w0, C, S, w0 int bits}
//  then xsT2         : uint4[NA*DET*2] delta-packed sinogram (2.95 MB):
//                      uint4 (a,d,g) = { half2(s_b[d], s_b[d+1]-s_b[d]) : b = 4g..4g+3 }
//                      + one zero uint4 at ZERO_IDX (OOB staging target)

// ---------------- fused prep + filter ----------------
// (out-zeroing removed: backproj is now single-writer and stores every pixel)
__global__ __launch_bounds__(256) void prep_filter_kernel(const float* __restrict__ x,
                                                          float4* __restrict__ tang,
                                                          unsigned* __restrict__ xsT2) {
    const int t = threadIdx.x;
    if (blockIdx.x >= 4 * NA) {
        const int pb = blockIdx.x - 4 * NA;
        int idx = pb * 256 + t;
        if (idx < NTILES * NA) {
            int tile = idx / NA;
            int a = idx - tile * NA;
            float th = (float)a * 0.017453292519943295f;
            float C = 255.5f * cosf(th);
            float S = 255.5f * sinf(th);
            int x0 = (tile & 31) << 4, y0 = (tile >> 5) << 4;
            float xga = (float)(2 * x0 - 511)        * (1.0f / 511.0f);
            float xgb = (float)(2 * (x0 + 15) - 511) * (1.0f / 511.0f);
            float yga = (float)(2 * y0 - 511)        * (1.0f / 511.0f);
            float ygb = (float)(2 * (y0 + 15) - 511) * (1.0f / 511.0f);
            float mn = 255.5f + fminf(xga * C, xgb * C) + fminf(-yga * S, -ygb * S);
            int w0 = (int)floorf(mn) - 1;     // -1 slack for fma rounding differences
            tang[idx] = make_float4(255.5f - (float)w0, C, S, __int_as_float(w0));
        }
        if (pb == 0 && t == 0) {
            uint4* z = (uint4*)xsT2 + ZERO_IDX;
            *z = make_uint4(0u, 0u, 0u, 0u);
        }
        return;
    }

    // ---- filter: wave w -> local batch lb=w>>1 (global 2z+lb), j-half h=w&1 ----
    __shared__ float xcols[2][DET];   // 4 KB
    __shared__ float g2s[1024];       // 4 KB  g2s[i] = g(|i-512|)
    __shared__ float part[4][DET];    // 8 KB

    const int a = blockIdx.x >> 2;
    const int z = blockIdx.x & 3;

    for (int i = t; i < 1024; i += 256) {
        int k = i - 512; if (k < 0) k = -k;
        float g = 0.0f;
        if (k == 0)      g = 0.5f;
        else if (k & 1)  { float fk = (float)k; g = -0.20264236728467558f / (fk * fk); }
        g2s[i] = g;
    }
    for (int i = t; i < 2 * DET; i += 256) {
        int b = i >> 9, j = i & 511;
        xcols[b][j] = x[((2 * z + b) * DET + j) * NA + a];
    }
    __syncthreads();

    const int w  = t >> 6, l = t & 63;
    const int lb = w >> 1, h = w & 1;
    const int d0 = l << 3;
    const int jstart = h << 8;

    float acc[8];
#pragma unroll
    for (int r = 0; r < 8; ++r) acc[r] = 0.0f;

    float W[16];
#pragma unroll
    for (int q = 0; q < 4; ++q)
        *(float4*)(W + 4 * q) = *(const float4*)(g2s + 504 + d0 - jstart + 4 * q);
    float xv[8];
    *(float4*)(xv)     = *(const float4*)(&xcols[lb][jstart]);
    *(float4*)(xv + 4) = *(const float4*)(&xcols[lb][jstart + 4]);

    for (int j0 = jstart; j0 < jstart + 256; j0 += 8) {
        float nxv[8], nW[8];
        const bool more = (j0 < jstart + 248);
        if (more) {
            *(float4*)(nxv)     = *(const float4*)(&xcols[lb][j0 + 8]);
            *(float4*)(nxv + 4) = *(const float4*)(&xcols[lb][j0 + 12]);
            *(float4*)(nW)      = *(const float4*)(g2s + 496 + d0 - j0);
            *(float4*)(nW + 4)  = *(const float4*)(g2s + 500 + d0 - j0);
        }
#pragma unroll
        for (int jj = 0; jj < 8; ++jj)
#pragma unroll
            for (int r = 0; r < 8; ++r)
                acc[r] = fmaf(xv[jj], W[8 + r - jj], acc[r]);
        if (more) {
#pragma unroll
            for (int i = 7; i >= 0; --i) W[i + 8] = W[i];
#pragma unroll
            for (int i = 0; i < 8; ++i) { W[i] = nW[i]; xv[i] = nxv[i]; }
        }
    }

    *(float4*)(&part[w][d0])     = *(const float4*)(acc);
    *(float4*)(&part[w][d0 + 4]) = *(const float4*)(acc + 4);
    __syncthreads();

    // reduce j-halves + delta pack: word = half2(v0, v1-v0); d=511 pairs with v1=0
    for (int i = t; i < DET; i += 256) {
        unsigned pw[2];
#pragma unroll
        for (int b = 0; b < 2; ++b) {
            float v0 = part[2 * b][i] + part[2 * b + 1][i];
            float v1 = 0.0f;
            if (i < DET - 1) v1 = part[2 * b][i + 1] + part[2 * b + 1][i + 1];
            __half2 hh = __halves2half2(__float2half_rn(v0), __float2half_rn(v1 - v0));
            pw[b] = *(unsigned*)&hh;
        }
        *(uint2*)(xsT2 + ((size_t)a * DET + i) * 8 + 4 * (z >> 1) + 2 * (z & 1)) =
            make_uint2(pw[0], pw[1]);
    }
}

// ---------------- backprojection: single-writer, DMA double-buffered staging ----------------
// grid 1024: one block per 16x16 tile, ALL 180 angles (no atomics, no out pre-zero).
// 1 thread = 1 pixel x 8 batches; staging via global_load_lds (no VGPR round trip,
// no ds_write); buffer for chunk c+1 filled while computing chunk c.
// CHUNK=20 (vs 10) doubles compute per barrier to compensate for 4 blocks/CU (vs 8).
__global__ __launch_bounds__(256, 4) void backproj_kernel(const float4* __restrict__ tang,
                                                          const uint4* __restrict__ xs,
                                                          float* __restrict__ out) {
    __shared__ uint4 win[2][NSLOT];   // 30.72 KB -> 4-5 blocks/CU (grid gives 4)

    const int tile = blockIdx.x;
    const int x0 = (tile & 31) << 4, y0 = (tile >> 5) << 4;
    const int t = threadIdx.x;
    const int px = t & 15, py = t >> 4;
    const float xg = (float)(2 * (x0 + px) - 511) * (1.0f / 511.0f);
    const float yg = (float)(2 * (y0 + py) - 511) * (1.0f / 511.0f);

    float acc[8];
#pragma unroll
    for (int j = 0; j < 8; ++j) acc[j] = 0.0f;

    const float4* ta = tang + (size_t)tile * NA;
    const uint4*  zs = xs + ZERO_IDX;

    // slot s (of 960): gg = s/480, ci = (s%480)/24, off = s%24
#define STAGE(CC, BB)                                                          \
    {                                                                          \
        int cc = (CC), bb = (BB);                                              \
        _Pragma("unroll")                                                      \
        for (int s0 = 0; s0 < NSLOT; s0 += 256) {                              \
            int s = s0 + t;                                                    \
            if (s < NSLOT) {                                                   \
                int gg  = (s >= CHUNK * WWIN) ? 1 : 0;                         \
                int r   = s - gg * (CHUNK * WWIN);                             \
                int ci  = r / WWIN;                                            \
                int off = r - ci * WWIN;                                       \
                int a   = cc * CHUNK + ci;                                     \
                int d   = __float_as_int(ta[a].w) + off;                       \
                const uint4* src = ((unsigned)d < 512u)                        \
                    ? &xs[((size_t)a * DET + d) * 2 + gg] : zs;                \
                async_copy16(&win[bb][s0 + (t & 192)], src);                   \
            }                                                                  \
        }                                                                      \
    }

    STAGE(0, 0);   // preloop: chunk 0 -> buffer 0

    for (int c = 0; c < NCH; ++c) {
        __syncthreads();   // drains DMA for buf[c&1]; prior chunk's readers done
        if (c + 1 < NCH)
            STAGE(c + 1, (c + 1) & 1);   // fills other buffer while we compute

        const uint4* base = &win[c & 1][0];
#pragma unroll
        for (int ci = 0; ci < CHUNK; ++ci) {
            float4 A = ta[c * CHUNK + ci];             // uniform -> s_load_dwordx4
            float yv = fmaf(xg, A.y, A.x) - yg * A.z;  // window-relative, >= 1
            float fi = floorf(yv);
            int  off = (int)fi;
            float wgt = yv - fi;
            auto pkw = __builtin_amdgcn_cvt_pkrtz(1.0f, wgt);   // (1, w) weights
            half2_t wv = *(half2_t*)&pkw;
            uint4 u0 = base[ci * WWIN + off];                  // ds_read_b128
            uint4 u1 = base[CHUNK * WWIN + ci * WWIN + off];   // ds_read_b128, +7680B imm
            acc[0] = __builtin_amdgcn_fdot2(*(half2_t*)&u0.x, wv, acc[0], false);
            acc[1] = __builtin_amdgcn_fdot2(*(half2_t*)&u0.y, wv, acc[1], false);
            acc[2] = __builtin_amdgcn_fdot2(*(half2_t*)&u0.z, wv, acc[2], false);
            acc[3] = __builtin_amdgcn_fdot2(*(half2_t*)&u0.w, wv, acc[3], false);
            acc[4] = __builtin_amdgcn_fdot2(*(half2_t*)&u1.x, wv, acc[4], false);
            acc[5] = __builtin_amdgcn_fdot2(*(half2_t*)&u1.y, wv, acc[5], false);
            acc[6] = __builtin_amdgcn_fdot2(*(half2_t*)&u1.z, wv, acc[6], false);
            acc[7] = __builtin_amdgcn_fdot2(*(half2_t*)&u1.w, wv, acc[7], false);
        }
    }

    // single writer per pixel: plain stores, circle mask + pi/(2A) folded in
    const float r2 = xg * xg + yg * yg;
    const float m  = (r2 <= 1.0f) ? 0.008726646259971648f : 0.0f;  // pi/360 masked
    const size_t pbase = ((size_t)(y0 + py) << 9) + (size_t)(x0 + px);
#pragma unroll
    for (int j = 0; j < 8; ++j)
        out[((size_t)j << 18) + pbase] = acc[j] * m;
}

extern "C" void kernel_launch(void* const* d_in, const int* in_sizes, int n_in,
                              void* d_out, int out_size, void* d_ws, size_t ws_size,
                              hipStream_t stream) {
    const float* x = (const float*)d_in[0];
    float* out = (float*)d_out;
    float* ws  = (float*)d_ws;

    float4*   tang = (float4*)ws;
    unsigned* xsT2 = (unsigned*)(ws + TANG_FLOATS);

    const int prep_blocks = (NTILES * NA + 255) / 256;   // 720
    prep_filter_kernel<<<4 * NA + prep_blocks, 256, 0, stream>>>(x, tang, xsT2);
    backproj_kernel<<<NTILES, 256, 0, stream>>>(tang, (const uint4*)xsT2, out);
}